// Round 4
// baseline (343.913 us; speedup 1.0000x reference)
//
#include <hip/hip_runtime.h>
#include <hip/hip_bf16.h>

#define B_ 2
#define L_ 256
#define T_ 250
#define D_ 1024
#define NH_ 16
#define DH_ 64
#define CRv_ 16
#define HID_ 64
#define CL_ 16
#define OUT_ 1024
#define MEMROWS_ 64001L
#define TCH_ 10
#define NTCH_ (T_ / TCH_)   // 25

typedef __attribute__((ext_vector_type(8))) short bf16x8;
typedef __attribute__((ext_vector_type(4))) float f32x4;

__device__ __forceinline__ unsigned short f2bf(float x) {
    __hip_bfloat16 h = __float2bfloat16(x);
    return __builtin_bit_cast(unsigned short, h);
}

__device__ __forceinline__ float exp2_fast(float x) {
#if __has_builtin(__builtin_amdgcn_exp2f)
    return __builtin_amdgcn_exp2f(x);
#else
    return __expf(x * 0.6931471805599453f);
#endif
}

// gelu(x) ~= x * sigmoid(1.5957691*(x + 0.044715 x^3)); exp2 form, log2e folded.
__device__ __forceinline__ float gelu_fast(float x) {
    float x2 = x * x;
    float z  = x * fmaf(x2, -0.1029445f, -2.3022055f);   // -(2u)*log2(e)
    float e  = exp2_fast(z);
    return x * __builtin_amdgcn_rcpf(1.0f + e);
}

// ---- Stage 1: v-MLP. One wave = one head. Swapped MFMA: A=W1^T, B=x.
// Lane (g,fl) ends with H[d=fl][f=16cn+4g+r] -> W2-dot is lane-local, reduce = 2 shuffles.
__global__ __launch_bounds__(256) void k_stage1(
    const float* __restrict__ mem, const float* __restrict__ dim_pe,
    const float* __restrict__ W1, const float* __restrict__ b1,
    const float* __restrict__ W2, const float* __restrict__ b2,
    unsigned short* __restrict__ vbuf)
{
    const int blk = blockIdx.x;                 // ((b*CL + cl)*NTCH + tch)*4 + nhg
    const int nhg  = blk & 3;
    const int tch  = (blk >> 2) % NTCH_;
    const int rest = (blk >> 2) / NTCH_;
    const int cl   = rest & (CL_ - 1);
    const int b    = rest >> 4;
    const int lane = threadIdx.x & 63;
    const int wv   = threadIdx.x >> 6;
    const int nh   = nhg * 4 + wv;
    const int g    = lane >> 4;                 // k = 8g + j (g<2 real); also output f-subrow
    const int fl   = lane & 15;
    const int kbase = (8 * g) & 15;
    const bool klive = (g < 2);

    const float* membase = mem + (long)b * MEMROWS_ * D_;
    unsigned short* vrow = vbuf + (long)(b * CL_ + cl) * T_ * D_;

    // Wave invariants: W1^T A-fragments (upper-K zeroed), per-lane b1/W2 rows, b2.
    bf16x8 bfragA[4];
    f32x4 ci[4];
    float w2l[4][4];
#pragma unroll
    for (int cn = 0; cn < 4; ++cn) {
        bf16x8 bf;
#pragma unroll
        for (int j = 0; j < 8; ++j) {
            float w = W1[(nh * CRv_ + kbase + j) * HID_ + cn * 16 + fl];
            bf[j] = klive ? (short)f2bf(w) : (short)0;
        }
        bfragA[cn] = bf;
#pragma unroll
        for (int r = 0; r < 4; ++r) {
            ci[cn][r]  = b1[nh * HID_ + cn * 16 + 4 * g + r];
            w2l[cn][r] = W2[nh * HID_ + cn * 16 + 4 * g + r];
        }
    }
    const float b2s = b2[nh];
    const int t0 = tch * TCH_;

#pragma unroll 1
    for (int ct = 0; ct < 4; ++ct) {
        const int d0 = nh * DH_ + ct * 16 + fl;

        float pef[8];
#pragma unroll
        for (int j = 0; j < 8; ++j)
            pef[j] = dim_pe[(kbase + j) * D_ + d0];

        const float* px[8];
        float xv[8];
#pragma unroll
        for (int j = 0; j < 8; ++j) {
            px[j] = membase + (size_t)((cl * CRv_ + kbase + j) * T_ + t0) * D_ + d0;
            xv[j] = *px[j];
            px[j] += D_;
        }

        for (int tt = 0; tt < TCH_; ++tt) {
            bf16x8 af;
#pragma unroll
            for (int j = 0; j < 8; ++j)
                af[j] = (short)f2bf(xv[j] + pef[j]);

            if (tt + 1 < TCH_) {
#pragma unroll
                for (int j = 0; j < 8; ++j) { xv[j] = *px[j]; px[j] += D_; }
            }

            f32x4 acc[4];
#pragma unroll
            for (int cn = 0; cn < 4; ++cn)
                acc[cn] = __builtin_amdgcn_mfma_f32_16x16x32_bf16(bfragA[cn], af, ci[cn], 0, 0, 0);

            // lane-local W2 dot over this lane's 16 f-values (4 independent chains)
            float p0 = 0.f, p1 = 0.f, p2 = 0.f, p3 = 0.f;
#pragma unroll
            for (int cn = 0; cn < 4; ++cn) {
                p0 = fmaf(gelu_fast(acc[cn][0]), w2l[cn][0], p0);
                p1 = fmaf(gelu_fast(acc[cn][1]), w2l[cn][1], p1);
                p2 = fmaf(gelu_fast(acc[cn][2]), w2l[cn][2], p2);
                p3 = fmaf(gelu_fast(acc[cn][3]), w2l[cn][3], p3);
            }
            float pr = (p0 + p1) + (p2 + p3);
            pr += __shfl_xor(pr, 16);
            pr += __shfl_xor(pr, 32);

            if (g == 0)
                vrow[(t0 + tt) * D_ + d0] = f2bf(pr + b2s);
        }
    }
}

// ---- Stage 2: h-MLP over t = tc*16+cr (pad rows -> nonsense). Same swapped structure.
__global__ __launch_bounds__(256) void k_stage2(
    const unsigned short* __restrict__ vbuf, const float* __restrict__ mem,
    const float* __restrict__ W1, const float* __restrict__ b1,
    const float* __restrict__ W2, const float* __restrict__ b2,
    float* __restrict__ hbuf)
{
    const int blk = blockIdx.x;                // ((b*CL + cl)*16 + tc)*4 + nhg
    const int nhg = blk & 3;
    const int tc  = (blk >> 2) & 15;
    const int cl  = (blk >> 6) & 15;
    const int b   = blk >> 10;
    const int lane = threadIdx.x & 63;
    const int wv   = threadIdx.x >> 6;
    const int nh   = nhg * 4 + wv;
    const int g    = lane >> 4;
    const int fl   = lane & 15;
    const int kbase = (8 * g) & 15;
    const bool klive = (g < 2);

    const unsigned short* vrow = vbuf + (long)(b * CL_ + cl) * T_ * D_;
    const float* nons = mem + ((long)b * MEMROWS_ + (long)L_ * T_) * D_;

    bf16x8 bfragA[4];
    f32x4 ci[4];
    float w2l[4][4];
#pragma unroll
    for (int cn = 0; cn < 4; ++cn) {
        bf16x8 bf;
#pragma unroll
        for (int j = 0; j < 8; ++j) {
            float w = W1[(nh * CRv_ + kbase + j) * HID_ + cn * 16 + fl];
            bf[j] = klive ? (short)f2bf(w) : (short)0;
        }
        bfragA[cn] = bf;
#pragma unroll
        for (int r = 0; r < 4; ++r) {
            ci[cn][r]  = b1[nh * HID_ + cn * 16 + 4 * g + r];
            w2l[cn][r] = W2[nh * HID_ + cn * 16 + 4 * g + r];
        }
    }
    const float b2s = b2[nh];

#pragma unroll 1
    for (int ct = 0; ct < 4; ++ct) {
        const int d0 = nh * DH_ + ct * 16 + fl;
        const unsigned short nvb = f2bf(nons[d0]);

        bf16x8 af;
#pragma unroll
        for (int j = 0; j < 8; ++j) {
            const int t   = tc * CRv_ + kbase + j;
            const int tcl = (t < T_) ? t : (T_ - 1);
            unsigned short us = vrow[tcl * D_ + d0];
            af[j] = (short)((t < T_) ? us : nvb);
        }

        f32x4 acc[4];
#pragma unroll
        for (int cn = 0; cn < 4; ++cn)
            acc[cn] = __builtin_amdgcn_mfma_f32_16x16x32_bf16(bfragA[cn], af, ci[cn], 0, 0, 0);

        float p0 = 0.f, p1 = 0.f, p2 = 0.f, p3 = 0.f;
#pragma unroll
        for (int cn = 0; cn < 4; ++cn) {
            p0 = fmaf(gelu_fast(acc[cn][0]), w2l[cn][0], p0);
            p1 = fmaf(gelu_fast(acc[cn][1]), w2l[cn][1], p1);
            p2 = fmaf(gelu_fast(acc[cn][2]), w2l[cn][2], p2);
            p3 = fmaf(gelu_fast(acc[cn][3]), w2l[cn][3], p3);
        }
        float pr = (p0 + p1) + (p2 + p3);
        pr += __shfl_xor(pr, 16);
        pr += __shfl_xor(pr, 32);

        if (g == 0)
            hbuf[(long)((b * CL_ + cl) * 16 + tc) * D_ + d0] = pr + b2s;
    }
}

// ---- Stage 3: C(512x1024) = H @ projW^T + bias (fp32 tiled GEMM)
__global__ __launch_bounds__(256) void k_proj(
    const float* __restrict__ H, const float* __restrict__ Wp,
    const float* __restrict__ bias, float* __restrict__ Cout)
{
    constexpr int BM = 32, BN = 64, BK = 32, K = 1024, NCOLB = OUT_ / BN; // 16
    __shared__ float Ht[BM][BK + 1];
    __shared__ float Wt[BN][BK + 1];

    const int bn = blockIdx.x % NCOLB;
    const int bm = blockIdx.x / NCOLB;
    const int tid = threadIdx.x;
    const int tx = tid & 15;
    const int ty = tid >> 4;
    const int lr = tid >> 3;
    const int lc = (tid & 7) << 2;

    float acc[2][4] = {};

    for (int k0 = 0; k0 < K; k0 += BK) {
        float4 hv  = *(const float4*)(H  + (long)(bm * BM + lr) * K + k0 + lc);
        float4 w0  = *(const float4*)(Wp + (long)(bn * BN + lr) * K + k0 + lc);
        float4 w1v = *(const float4*)(Wp + (long)(bn * BN + 32 + lr) * K + k0 + lc);
        Ht[lr][lc + 0] = hv.x;  Ht[lr][lc + 1] = hv.y;  Ht[lr][lc + 2] = hv.z;  Ht[lr][lc + 3] = hv.w;
        Wt[lr][lc + 0] = w0.x;  Wt[lr][lc + 1] = w0.y;  Wt[lr][lc + 2] = w0.z;  Wt[lr][lc + 3] = w0.w;
        Wt[32 + lr][lc + 0] = w1v.x; Wt[32 + lr][lc + 1] = w1v.y; Wt[32 + lr][lc + 2] = w1v.z; Wt[32 + lr][lc + 3] = w1v.w;
        __syncthreads();

#pragma unroll
        for (int kk = 0; kk < BK; ++kk) {
            float va0 = Ht[ty * 2 + 0][kk];
            float va1 = Ht[ty * 2 + 1][kk];
            float vb0 = Wt[tx * 4 + 0][kk];
            float vb1 = Wt[tx * 4 + 1][kk];
            float vb2 = Wt[tx * 4 + 2][kk];
            float vb3 = Wt[tx * 4 + 3][kk];
            acc[0][0] = fmaf(va0, vb0, acc[0][0]);
            acc[0][1] = fmaf(va0, vb1, acc[0][1]);
            acc[0][2] = fmaf(va0, vb2, acc[0][2]);
            acc[0][3] = fmaf(va0, vb3, acc[0][3]);
            acc[1][0] = fmaf(va1, vb0, acc[1][0]);
            acc[1][1] = fmaf(va1, vb1, acc[1][1]);
            acc[1][2] = fmaf(va1, vb2, acc[1][2]);
            acc[1][3] = fmaf(va1, vb3, acc[1][3]);
        }
        __syncthreads();
    }

#pragma unroll
    for (int i = 0; i < 2; ++i) {
#pragma unroll
        for (int jj = 0; jj < 4; ++jj) {
            int r = bm * BM + ty * 2 + i;
            int c = bn * BN + tx * 4 + jj;
            Cout[(long)r * OUT_ + c] = acc[i][jj] + bias[c];
        }
    }
}

extern "C" void kernel_launch(void* const* d_in, const int* in_sizes, int n_in,
                              void* d_out, int out_size, void* d_ws, size_t ws_size,
                              hipStream_t stream) {
    const float* mem    = (const float*)d_in[0];
    const float* dim_pe = (const float*)d_in[2];
    const float* vW1    = (const float*)d_in[3];
    const float* vb1    = (const float*)d_in[4];
    const float* vW2    = (const float*)d_in[5];
    const float* vb2    = (const float*)d_in[6];
    const float* hW1    = (const float*)d_in[7];
    const float* hb1    = (const float*)d_in[8];
    const float* hW2    = (const float*)d_in[9];
    const float* hb2    = (const float*)d_in[10];
    const float* projW  = (const float*)d_in[11];
    const float* projb  = (const float*)d_in[12];
    float* out = (float*)d_out;

    unsigned short* vbuf = (unsigned short*)d_ws;                       // bf16, 16 MB
    float* hbuf = (float*)((char*)d_ws + (size_t)B_ * CL_ * T_ * D_ * sizeof(unsigned short));

    k_stage1<<<B_ * CL_ * NTCH_ * 4, 256, 0, stream>>>(mem, dim_pe, vW1, vb1, vW2, vb2, vbuf);
    k_stage2<<<B_ * CL_ * 16 * 4, 256, 0, stream>>>(vbuf, mem, hW1, hb1, hW2, hb2, hbuf);
    k_proj<<<(512 / 32) * (OUT_ / 64), 256, 0, stream>>>(hbuf, projW, projb, out);
}

// Round 6
// 259.761 us; speedup vs baseline: 1.3240x; 1.3240x over previous
//
#include <hip/hip_runtime.h>
#include <hip/hip_bf16.h>

#define B_ 2
#define L_ 256
#define T_ 250
#define D_ 1024
#define NH_ 16
#define DH_ 64
#define CRv_ 16
#define HID_ 64
#define CL_ 16
#define OUT_ 1024
#define MEMROWS_ 64001L
#define TCH_ 10
#define NTCH_ (T_ / TCH_)   // 25

typedef __attribute__((ext_vector_type(2))) _Float16 h16x2;
typedef __attribute__((ext_vector_type(8))) _Float16 h16x8;
typedef __attribute__((ext_vector_type(4))) float f32x4;

__device__ __forceinline__ h16x2 cvt_pk(float lo, float hi) {
    return __builtin_bit_cast(h16x2, __builtin_amdgcn_cvt_pkrtz(lo, hi));
}

struct H4 { h16x2 a, b, c, d; };
__device__ __forceinline__ h16x8 packH4(h16x2 a, h16x2 b, h16x2 c, h16x2 d) {
    H4 h{a, b, c, d};
    return __builtin_bit_cast(h16x8, h);
}
__device__ __forceinline__ h16x2 hsplat(float x) {
    _Float16 h = (_Float16)x;
    h16x2 v; v[0] = h; v[1] = h;
    return v;
}

// Packed-f16 gelu * w2 accumulate. E(t') = t'*P~(t'^2), t' = clamp(x/2, +-1.75).
// P~ Newton-fit to erf(sqrt(2)*t')/t'; |gelu err| <= ~6e-3 over |x|<=7.
__device__ __forceinline__ void gelu_w2_pk(h16x2 a, h16x2 w, h16x2& pacc) {
    const h16x2 C0 = hsplat(1.5957600f);
    const h16x2 C1 = hsplat(-1.0445624f);
    const h16x2 C2 = hsplat(0.5417632f);
    const h16x2 C3 = hsplat(-0.15817472f);
    const h16x2 C4 = hsplat(0.018604288f);
    h16x2 ha = a * hsplat(0.5f);
    h16x2 t  = __builtin_elementwise_min(__builtin_elementwise_max(ha, hsplat(-1.75f)), hsplat(1.75f));
    h16x2 s  = t * t;
    h16x2 p  = C4 * s + C3;
    p = p * s + C2;
    p = p * s + C1;
    p = p * s + C0;
    h16x2 e  = t * p;          // ~erf(x/sqrt2)
    h16x2 g  = ha * e + ha;    // gelu(x)
    pacc = g * w + pacc;
}

// ---- Stage 1: v-MLP. One wave = one head. Swapped MFMA (f16): A=W1^T, B=x.
__global__ __launch_bounds__(256) void k_stage1(
    const float* __restrict__ mem, const float* __restrict__ dim_pe,
    const float* __restrict__ W1, const float* __restrict__ b1,
    const float* __restrict__ W2, const float* __restrict__ b2,
    _Float16* __restrict__ vbuf)
{
    const int blk = blockIdx.x;                 // ((b*CL + cl)*NTCH + tch)*4 + nhg
    const int nhg  = blk & 3;
    const int tch  = (blk >> 2) % NTCH_;
    const int rest = (blk >> 2) / NTCH_;
    const int cl   = rest & (CL_ - 1);
    const int b    = rest >> 4;
    const int lane = threadIdx.x & 63;
    const int wv   = threadIdx.x >> 6;
    const int nh   = nhg * 4 + wv;
    const int g    = lane >> 4;                 // k = 8g + j (g<2 real); also output f-subrow
    const int fl   = lane & 15;
    const int kbase = (8 * g) & 15;
    const bool klive = (g < 2);

    const float* membase = mem + (long)b * MEMROWS_ * D_;
    _Float16* vrow = vbuf + (long)(b * CL_ + cl) * T_ * D_;

    // Wave invariants: W1^T A-fragments (upper-K zeroed), b1 in MFMA C, W2 packed f16.
    h16x8 bfragA[4];
    f32x4 ci[4];
    h16x2 w2pk[8];
#pragma unroll
    for (int cn = 0; cn < 4; ++cn) {
        h16x2 q[4];
#pragma unroll
        for (int jp = 0; jp < 4; ++jp) {
            float w0 = W1[(nh * CRv_ + kbase + 2 * jp + 0) * HID_ + cn * 16 + fl];
            float w1 = W1[(nh * CRv_ + kbase + 2 * jp + 1) * HID_ + cn * 16 + fl];
            h16x2 qq; qq[0] = klive ? (_Float16)w0 : (_Float16)0.f;
                      qq[1] = klive ? (_Float16)w1 : (_Float16)0.f;
            q[jp] = qq;
        }
        bfragA[cn] = packH4(q[0], q[1], q[2], q[3]);
#pragma unroll
        for (int r = 0; r < 4; ++r) ci[cn][r] = b1[nh * HID_ + cn * 16 + 4 * g + r];
        h16x2 wlo; wlo[0] = (_Float16)W2[nh * HID_ + cn * 16 + 4 * g + 0];
                   wlo[1] = (_Float16)W2[nh * HID_ + cn * 16 + 4 * g + 1];
        h16x2 whi; whi[0] = (_Float16)W2[nh * HID_ + cn * 16 + 4 * g + 2];
                   whi[1] = (_Float16)W2[nh * HID_ + cn * 16 + 4 * g + 3];
        w2pk[2 * cn + 0] = wlo;
        w2pk[2 * cn + 1] = whi;
    }
    const float b2s = b2[nh];
    const int t0 = tch * TCH_;

#pragma unroll 1
    for (int ct = 0; ct < 4; ++ct) {
        const int d0 = nh * DH_ + ct * 16 + fl;

        float pef[8];
#pragma unroll
        for (int j = 0; j < 8; ++j)
            pef[j] = dim_pe[(kbase + j) * D_ + d0];

        const float* px[8];
        float xv[8];
#pragma unroll
        for (int j = 0; j < 8; ++j) {
            px[j] = membase + (size_t)((cl * CRv_ + kbase + j) * T_ + t0) * D_ + d0;
            xv[j] = *px[j];
            px[j] += D_;
        }

        for (int tt = 0; tt < TCH_; ++tt) {
            h16x2 q0 = cvt_pk(xv[0] + pef[0], xv[1] + pef[1]);
            h16x2 q1 = cvt_pk(xv[2] + pef[2], xv[3] + pef[3]);
            h16x2 q2 = cvt_pk(xv[4] + pef[4], xv[5] + pef[5]);
            h16x2 q3 = cvt_pk(xv[6] + pef[6], xv[7] + pef[7]);
            h16x8 af = packH4(q0, q1, q2, q3);

            if (tt + 1 < TCH_) {
#pragma unroll
                for (int j = 0; j < 8; ++j) { xv[j] = *px[j]; px[j] += D_; }
            }

            f32x4 acc[4];
#pragma unroll
            for (int cn = 0; cn < 4; ++cn)
                acc[cn] = __builtin_amdgcn_mfma_f32_16x16x32_f16(bfragA[cn], af, ci[cn], 0, 0, 0);

            h16x2 pc0 = hsplat(0.f), pc1 = hsplat(0.f);
#pragma unroll
            for (int cn = 0; cn < 4; ++cn) {
                h16x2 a01 = cvt_pk(acc[cn][0], acc[cn][1]);
                h16x2 a23 = cvt_pk(acc[cn][2], acc[cn][3]);
                gelu_w2_pk(a01, w2pk[2 * cn + 0], pc0);
                gelu_w2_pk(a23, w2pk[2 * cn + 1], pc1);
            }
            float pr = ((float)pc0[0] + (float)pc0[1]) + ((float)pc1[0] + (float)pc1[1]);
            pr += __shfl_xor(pr, 16);
            pr += __shfl_xor(pr, 32);

            if (g == 0)
                vrow[(t0 + tt) * D_ + d0] = (_Float16)(pr + b2s);
        }
    }
}

// ---- Stage 2: h-MLP over t = tc*16+cr (pad rows -> nonsense). Same structure.
__global__ __launch_bounds__(256) void k_stage2(
    const _Float16* __restrict__ vbuf, const float* __restrict__ mem,
    const float* __restrict__ W1, const float* __restrict__ b1,
    const float* __restrict__ W2, const float* __restrict__ b2,
    float* __restrict__ hbuf)
{
    const int blk = blockIdx.x;                // ((b*CL + cl)*16 + tc)*4 + nhg
    const int nhg = blk & 3;
    const int tc  = (blk >> 2) & 15;
    const int cl  = (blk >> 6) & 15;
    const int b   = blk >> 10;
    const int lane = threadIdx.x & 63;
    const int wv   = threadIdx.x >> 6;
    const int nh   = nhg * 4 + wv;
    const int g    = lane >> 4;
    const int fl   = lane & 15;
    const int kbase = (8 * g) & 15;
    const bool klive = (g < 2);

    const _Float16* vrow = vbuf + (long)(b * CL_ + cl) * T_ * D_;
    const float* nons = mem + ((long)b * MEMROWS_ + (long)L_ * T_) * D_;

    h16x8 bfragA[4];
    f32x4 ci[4];
    h16x2 w2pk[8];
#pragma unroll
    for (int cn = 0; cn < 4; ++cn) {
        h16x2 q[4];
#pragma unroll
        for (int jp = 0; jp < 4; ++jp) {
            float w0 = W1[(nh * CRv_ + kbase + 2 * jp + 0) * HID_ + cn * 16 + fl];
            float w1 = W1[(nh * CRv_ + kbase + 2 * jp + 1) * HID_ + cn * 16 + fl];
            h16x2 qq; qq[0] = klive ? (_Float16)w0 : (_Float16)0.f;
                      qq[1] = klive ? (_Float16)w1 : (_Float16)0.f;
            q[jp] = qq;
        }
        bfragA[cn] = packH4(q[0], q[1], q[2], q[3]);
#pragma unroll
        for (int r = 0; r < 4; ++r) ci[cn][r] = b1[nh * HID_ + cn * 16 + 4 * g + r];
        h16x2 wlo; wlo[0] = (_Float16)W2[nh * HID_ + cn * 16 + 4 * g + 0];
                   wlo[1] = (_Float16)W2[nh * HID_ + cn * 16 + 4 * g + 1];
        h16x2 whi; whi[0] = (_Float16)W2[nh * HID_ + cn * 16 + 4 * g + 2];
                   whi[1] = (_Float16)W2[nh * HID_ + cn * 16 + 4 * g + 3];
        w2pk[2 * cn + 0] = wlo;
        w2pk[2 * cn + 1] = whi;
    }
    const float b2s = b2[nh];

#pragma unroll 1
    for (int ct = 0; ct < 4; ++ct) {
        const int d0 = nh * DH_ + ct * 16 + fl;
        const _Float16 nv = (_Float16)nons[d0];

        h16x2 q[4];
#pragma unroll
        for (int jp = 0; jp < 4; ++jp) {
            h16x2 qq;
#pragma unroll
            for (int e = 0; e < 2; ++e) {
                const int t   = tc * CRv_ + kbase + 2 * jp + e;
                const int tcl = (t < T_) ? t : (T_ - 1);
                _Float16 us = vrow[tcl * D_ + d0];
                qq[e] = (t < T_) ? us : nv;
            }
            q[jp] = qq;
        }
        h16x8 af = packH4(q[0], q[1], q[2], q[3]);

        f32x4 acc[4];
#pragma unroll
        for (int cn = 0; cn < 4; ++cn)
            acc[cn] = __builtin_amdgcn_mfma_f32_16x16x32_f16(bfragA[cn], af, ci[cn], 0, 0, 0);

        h16x2 pc0 = hsplat(0.f), pc1 = hsplat(0.f);
#pragma unroll
        for (int cn = 0; cn < 4; ++cn) {
            h16x2 a01 = cvt_pk(acc[cn][0], acc[cn][1]);
            h16x2 a23 = cvt_pk(acc[cn][2], acc[cn][3]);
            gelu_w2_pk(a01, w2pk[2 * cn + 0], pc0);
            gelu_w2_pk(a23, w2pk[2 * cn + 1], pc1);
        }
        float pr = ((float)pc0[0] + (float)pc0[1]) + ((float)pc1[0] + (float)pc1[1]);
        pr += __shfl_xor(pr, 16);
        pr += __shfl_xor(pr, 32);

        if (g == 0)
            hbuf[(long)((b * CL_ + cl) * 16 + tc) * D_ + d0] = pr + b2s;
    }
}

// ---- Stage 3: C(512x1024) = H @ projW^T + bias (fp32 tiled GEMM)
__global__ __launch_bounds__(256) void k_proj(
    const float* __restrict__ H, const float* __restrict__ Wp,
    const float* __restrict__ bias, float* __restrict__ Cout)
{
    constexpr int BM = 32, BN = 64, BK = 32, K = 1024, NCOLB = OUT_ / BN; // 16
    __shared__ float Ht[BM][BK + 1];
    __shared__ float Wt[BN][BK + 1];

    const int bn = blockIdx.x % NCOLB;
    const int bm = blockIdx.x / NCOLB;
    const int tid = threadIdx.x;
    const int tx = tid & 15;
    const int ty = tid >> 4;
    const int lr = tid >> 3;
    const int lc = (tid & 7) << 2;

    float acc[2][4] = {};

    for (int k0 = 0; k0 < K; k0 += BK) {
        float4 hv  = *(const float4*)(H  + (long)(bm * BM + lr) * K + k0 + lc);
        float4 w0  = *(const float4*)(Wp + (long)(bn * BN + lr) * K + k0 + lc);
        float4 w1v = *(const float4*)(Wp + (long)(bn * BN + 32 + lr) * K + k0 + lc);
        Ht[lr][lc + 0] = hv.x;  Ht[lr][lc + 1] = hv.y;  Ht[lr][lc + 2] = hv.z;  Ht[lr][lc + 3] = hv.w;
        Wt[lr][lc + 0] = w0.x;  Wt[lr][lc + 1] = w0.y;  Wt[lr][lc + 2] = w0.z;  Wt[lr][lc + 3] = w0.w;
        Wt[32 + lr][lc + 0] = w1v.x; Wt[32 + lr][lc + 1] = w1v.y; Wt[32 + lr][lc + 2] = w1v.z; Wt[32 + lr][lc + 3] = w1v.w;
        __syncthreads();

#pragma unroll
        for (int kk = 0; kk < BK; ++kk) {
            float va0 = Ht[ty * 2 + 0][kk];
            float va1 = Ht[ty * 2 + 1][kk];
            float vb0 = Wt[tx * 4 + 0][kk];
            float vb1 = Wt[tx * 4 + 1][kk];
            float vb2 = Wt[tx * 4 + 2][kk];
            float vb3 = Wt[tx * 4 + 3][kk];
            acc[0][0] = fmaf(va0, vb0, acc[0][0]);
            acc[0][1] = fmaf(va0, vb1, acc[0][1]);
            acc[0][2] = fmaf(va0, vb2, acc[0][2]);
            acc[0][3] = fmaf(va0, vb3, acc[0][3]);
            acc[1][0] = fmaf(va1, vb0, acc[1][0]);
            acc[1][1] = fmaf(va1, vb1, acc[1][1]);
            acc[1][2] = fmaf(va1, vb2, acc[1][2]);
            acc[1][3] = fmaf(va1, vb3, acc[1][3]);
        }
        __syncthreads();
    }

#pragma unroll
    for (int i = 0; i < 2; ++i) {
#pragma unroll
        for (int jj = 0; jj < 4; ++jj) {
            int r = bm * BM + ty * 2 + i;
            int c = bn * BN + tx * 4 + jj;
            Cout[(long)r * OUT_ + c] = acc[i][jj] + bias[c];
        }
    }
}

extern "C" void kernel_launch(void* const* d_in, const int* in_sizes, int n_in,
                              void* d_out, int out_size, void* d_ws, size_t ws_size,
                              hipStream_t stream) {
    const float* mem    = (const float*)d_in[0];
    const float* dim_pe = (const float*)d_in[2];
    const float* vW1    = (const float*)d_in[3];
    const float* vb1    = (const float*)d_in[4];
    const float* vW2    = (const float*)d_in[5];
    const float* vb2    = (const float*)d_in[6];
    const float* hW1    = (const float*)d_in[7];
    const float* hb1    = (const float*)d_in[8];
    const float* hW2    = (const float*)d_in[9];
    const float* hb2    = (const float*)d_in[10];
    const float* projW  = (const float*)d_in[11];
    const float* projb  = (const float*)d_in[12];
    float* out = (float*)d_out;

    _Float16* vbuf = (_Float16*)d_ws;                                   // f16, 16 MB
    float* hbuf = (float*)((char*)d_ws + (size_t)B_ * CL_ * T_ * D_ * sizeof(_Float16));

    k_stage1<<<B_ * CL_ * NTCH_ * 4, 256, 0, stream>>>(mem, dim_pe, vW1, vb1, vW2, vb2, vbuf);
    k_stage2<<<B_ * CL_ * 16 * 4, 256, 0, stream>>>(vbuf, mem, hW1, hb1, hW2, hb2, hbuf);
    k_proj<<<(512 / 32) * (OUT_ / 64), 256, 0, stream>>>(hbuf, projW, projb, out);
}

// Round 7
// 230.601 us; speedup vs baseline: 1.4914x; 1.1265x over previous
//
#include <hip/hip_runtime.h>
#include <hip/hip_bf16.h>

#define B_ 2
#define L_ 256
#define T_ 250
#define D_ 1024
#define NH_ 16
#define DH_ 64
#define CRv_ 16
#define HID_ 64
#define CL_ 16
#define OUT_ 1024
#define MEMROWS_ 64001L
#define TCH_ 10
#define NTCH_ (T_ / TCH_)   // 25

#define AS1 __attribute__((address_space(1)))
#define AS3 __attribute__((address_space(3)))

typedef __attribute__((ext_vector_type(2))) _Float16 h16x2;
typedef __attribute__((ext_vector_type(8))) _Float16 h16x8;
typedef __attribute__((ext_vector_type(4))) float f32x4;

__device__ __forceinline__ h16x2 cvt_pk(float lo, float hi) {
    return __builtin_bit_cast(h16x2, __builtin_amdgcn_cvt_pkrtz(lo, hi));
}

struct H4 { h16x2 a, b, c, d; };
__device__ __forceinline__ h16x8 packH4(h16x2 a, h16x2 b, h16x2 c, h16x2 d) {
    H4 h{a, b, c, d};
    return __builtin_bit_cast(h16x8, h);
}
__device__ __forceinline__ h16x2 hsplat(float x) {
    _Float16 h = (_Float16)x;
    h16x2 v; v[0] = h; v[1] = h;
    return v;
}

// Packed-f16 gelu * w2 accumulate. E(t') = t'*P~(t'^2), t' = clamp(x/2, +-1.75).
__device__ __forceinline__ void gelu_w2_pk(h16x2 a, h16x2 w, h16x2& pacc) {
    const h16x2 C0 = hsplat(1.5957600f);
    const h16x2 C1 = hsplat(-1.0445624f);
    const h16x2 C2 = hsplat(0.5417632f);
    const h16x2 C3 = hsplat(-0.15817472f);
    const h16x2 C4 = hsplat(0.018604288f);
    h16x2 ha = a * hsplat(0.5f);
    h16x2 t  = __builtin_elementwise_min(__builtin_elementwise_max(ha, hsplat(-1.75f)), hsplat(1.75f));
    h16x2 s  = t * t;
    h16x2 p  = C4 * s + C3;
    p = p * s + C2;
    p = p * s + C1;
    p = p * s + C0;
    h16x2 e  = t * p;
    h16x2 g  = ha * e + ha;
    pacc = g * w + pacc;
}

#define WAITV(n) asm volatile("s_waitcnt vmcnt(" #n ")" ::: "memory")
#define MEMBAR() asm volatile("" ::: "memory")

// ---- Stage 1: v-MLP. One wave = one head. LDS-staged x-tile (16cr x 64d f32),
// double-buffered over t via global_load_lds dwordx4 with counted vmcnt.
__global__ __launch_bounds__(256) void k_stage1(
    const float* __restrict__ mem, const float* __restrict__ dim_pe,
    const float* __restrict__ W1, const float* __restrict__ b1,
    const float* __restrict__ W2, const float* __restrict__ b2,
    _Float16* __restrict__ vbuf)
{
    __shared__ float stage[4][2][1024];   // [wave][buf][16 rows x 64 cols]

    const int blk = blockIdx.x;                 // ((b*CL + cl)*NTCH + tch)*4 + nhg
    const int nhg  = blk & 3;
    const int tch  = (blk >> 2) % NTCH_;
    const int rest = (blk >> 2) / NTCH_;
    const int cl   = rest & (CL_ - 1);
    const int b    = rest >> 4;
    const int lane = threadIdx.x & 63;
    const int wv   = threadIdx.x >> 6;
    const int nh   = nhg * 4 + wv;
    const int g    = lane >> 4;                 // k-group; also output f-subrow group
    const int fl   = lane & 15;
    const int kbase = (8 * g) & 15;
    const bool klive = (g < 2);

    const float* membase = mem + (long)b * MEMROWS_ * D_;
    _Float16* vrow = vbuf + (long)(b * CL_ + cl) * T_ * D_;
    const int t0 = tch * TCH_;

    // dim_pe fragments for all 4 ct tiles (32 f32 regs)
    float pef[4][8];
#pragma unroll
    for (int ct = 0; ct < 4; ++ct)
#pragma unroll
        for (int j = 0; j < 8; ++j)
            pef[ct][j] = dim_pe[(kbase + j) * D_ + nh * DH_ + ct * 16 + fl];

    // Wave invariants: W1^T A-fragments (upper-K zeroed), b1 in MFMA C, W2 packed f16.
    h16x8 bfragA[4];
    f32x4 ci[4];
    h16x2 w2pk[8];
#pragma unroll
    for (int cn = 0; cn < 4; ++cn) {
        h16x2 q[4];
#pragma unroll
        for (int jp = 0; jp < 4; ++jp) {
            float w0 = W1[(nh * CRv_ + kbase + 2 * jp + 0) * HID_ + cn * 16 + fl];
            float w1 = W1[(nh * CRv_ + kbase + 2 * jp + 1) * HID_ + cn * 16 + fl];
            h16x2 qq; qq[0] = klive ? (_Float16)w0 : (_Float16)0.f;
                      qq[1] = klive ? (_Float16)w1 : (_Float16)0.f;
            q[jp] = qq;
        }
        bfragA[cn] = packH4(q[0], q[1], q[2], q[3]);
#pragma unroll
        for (int r = 0; r < 4; ++r) ci[cn][r] = b1[nh * HID_ + cn * 16 + 4 * g + r];
        h16x2 wlo; wlo[0] = (_Float16)W2[nh * HID_ + cn * 16 + 4 * g + 0];
                   wlo[1] = (_Float16)W2[nh * HID_ + cn * 16 + 4 * g + 1];
        h16x2 whi; whi[0] = (_Float16)W2[nh * HID_ + cn * 16 + 4 * g + 2];
                   whi[1] = (_Float16)W2[nh * HID_ + cn * 16 + 4 * g + 3];
        w2pk[2 * cn + 0] = wlo;
        w2pk[2 * cn + 1] = whi;
    }
    const float b2s = b2[nh];

    // Staging pointers: instruction i loads rows i*4 + lane/16, col-quad lane%16.
    const int srow = lane >> 4;
    const int scol = (lane & 15) * 4;
    const float* gpa = membase + ((size_t)(cl * CRv_ +  0 + srow) * T_ + t0) * D_ + nh * DH_ + scol;
    const float* gpb = membase + ((size_t)(cl * CRv_ +  4 + srow) * T_ + t0) * D_ + nh * DH_ + scol;
    const float* gpc = membase + ((size_t)(cl * CRv_ +  8 + srow) * T_ + t0) * D_ + nh * DH_ + scol;
    const float* gpd = membase + ((size_t)(cl * CRv_ + 12 + srow) * T_ + t0) * D_ + nh * DH_ + scol;

#define ISSUE(c) do { \
    __builtin_amdgcn_global_load_lds((const AS1 void*)gpa, (AS3 void*)(&stage[wv][(c)][0 * 256]), 16, 0, 0); \
    __builtin_amdgcn_global_load_lds((const AS1 void*)gpb, (AS3 void*)(&stage[wv][(c)][1 * 256]), 16, 0, 0); \
    __builtin_amdgcn_global_load_lds((const AS1 void*)gpc, (AS3 void*)(&stage[wv][(c)][2 * 256]), 16, 0, 0); \
    __builtin_amdgcn_global_load_lds((const AS1 void*)gpd, (AS3 void*)(&stage[wv][(c)][3 * 256]), 16, 0, 0); \
    gpa += D_; gpb += D_; gpc += D_; gpd += D_; } while (0)

    ISSUE(0);                                   // prefetch t0
    int cur = 0;

    for (int tt = 0; tt < TCH_; ++tt) {
        if (tt + 1 < TCH_) ISSUE(cur ^ 1);      // prefetch t+1
        // counted waits: pending allowed = [new loads] + [1 store from prev iter]
        if (tt == 0)            WAITV(4);
        else if (tt == TCH_-1)  WAITV(1);
        else                    WAITV(5);

        const float* bufp = &stage[wv][cur][0];
        _Float16 vkeep = (_Float16)0.f;

#pragma unroll
        for (int ct = 0; ct < 4; ++ct) {
            float a0 = bufp[(kbase + 0) * 64 + ct * 16 + fl] + pef[ct][0];
            float a1 = bufp[(kbase + 1) * 64 + ct * 16 + fl] + pef[ct][1];
            float a2 = bufp[(kbase + 2) * 64 + ct * 16 + fl] + pef[ct][2];
            float a3 = bufp[(kbase + 3) * 64 + ct * 16 + fl] + pef[ct][3];
            float a4 = bufp[(kbase + 4) * 64 + ct * 16 + fl] + pef[ct][4];
            float a5 = bufp[(kbase + 5) * 64 + ct * 16 + fl] + pef[ct][5];
            float a6 = bufp[(kbase + 6) * 64 + ct * 16 + fl] + pef[ct][6];
            float a7 = bufp[(kbase + 7) * 64 + ct * 16 + fl] + pef[ct][7];
            h16x8 af = packH4(cvt_pk(a0, a1), cvt_pk(a2, a3), cvt_pk(a4, a5), cvt_pk(a6, a7));

            f32x4 acc[4];
#pragma unroll
            for (int cn = 0; cn < 4; ++cn)
                acc[cn] = __builtin_amdgcn_mfma_f32_16x16x32_f16(bfragA[cn], af, ci[cn], 0, 0, 0);

            h16x2 pc0 = hsplat(0.f), pc1 = hsplat(0.f);
#pragma unroll
            for (int cn = 0; cn < 4; ++cn) {
                h16x2 a01 = cvt_pk(acc[cn][0], acc[cn][1]);
                h16x2 a23 = cvt_pk(acc[cn][2], acc[cn][3]);
                gelu_w2_pk(a01, w2pk[2 * cn + 0], pc0);
                gelu_w2_pk(a23, w2pk[2 * cn + 1], pc1);
            }
            float pr = ((float)pc0[0] + (float)pc0[1]) + ((float)pc1[0] + (float)pc1[1]);
            pr += __shfl_xor(pr, 16);
            pr += __shfl_xor(pr, 32);           // all 64 lanes now hold out(d = ct*16+fl)

            if (g == ct) vkeep = (_Float16)(pr + b2s);
        }
        // one contiguous 2B/lane store: lane (g,fl) owns d = g*16+fl
        vrow[(size_t)(t0 + tt) * D_ + nh * DH_ + g * 16 + fl] = vkeep;
        MEMBAR();                                // pin store before next ISSUE
        cur ^= 1;
    }
#undef ISSUE
}

// ---- Stage 2: h-MLP over t = tc*16+cr (pad rows -> nonsense). Same as R6.
__global__ __launch_bounds__(256) void k_stage2(
    const _Float16* __restrict__ vbuf, const float* __restrict__ mem,
    const float* __restrict__ W1, const float* __restrict__ b1,
    const float* __restrict__ W2, const float* __restrict__ b2,
    float* __restrict__ hbuf)
{
    const int blk = blockIdx.x;                // ((b*CL + cl)*16 + tc)*4 + nhg
    const int nhg = blk & 3;
    const int tc  = (blk >> 2) & 15;
    const int cl  = (blk >> 6) & 15;
    const int b   = blk >> 10;
    const int lane = threadIdx.x & 63;
    const int wv   = threadIdx.x >> 6;
    const int nh   = nhg * 4 + wv;
    const int g    = lane >> 4;
    const int fl   = lane & 15;
    const int kbase = (8 * g) & 15;
    const bool klive = (g < 2);

    const _Float16* vrow = vbuf + (long)(b * CL_ + cl) * T_ * D_;
    const float* nons = mem + ((long)b * MEMROWS_ + (long)L_ * T_) * D_;

    h16x8 bfragA[4];
    f32x4 ci[4];
    h16x2 w2pk[8];
#pragma unroll
    for (int cn = 0; cn < 4; ++cn) {
        h16x2 q[4];
#pragma unroll
        for (int jp = 0; jp < 4; ++jp) {
            float w0 = W1[(nh * CRv_ + kbase + 2 * jp + 0) * HID_ + cn * 16 + fl];
            float w1 = W1[(nh * CRv_ + kbase + 2 * jp + 1) * HID_ + cn * 16 + fl];
            h16x2 qq; qq[0] = klive ? (_Float16)w0 : (_Float16)0.f;
                      qq[1] = klive ? (_Float16)w1 : (_Float16)0.f;
            q[jp] = qq;
        }
        bfragA[cn] = packH4(q[0], q[1], q[2], q[3]);
#pragma unroll
        for (int r = 0; r < 4; ++r) ci[cn][r] = b1[nh * HID_ + cn * 16 + 4 * g + r];
        h16x2 wlo; wlo[0] = (_Float16)W2[nh * HID_ + cn * 16 + 4 * g + 0];
                   wlo[1] = (_Float16)W2[nh * HID_ + cn * 16 + 4 * g + 1];
        h16x2 whi; whi[0] = (_Float16)W2[nh * HID_ + cn * 16 + 4 * g + 2];
                   whi[1] = (_Float16)W2[nh * HID_ + cn * 16 + 4 * g + 3];
        w2pk[2 * cn + 0] = wlo;
        w2pk[2 * cn + 1] = whi;
    }
    const float b2s = b2[nh];

#pragma unroll 1
    for (int ct = 0; ct < 4; ++ct) {
        const int d0 = nh * DH_ + ct * 16 + fl;
        const _Float16 nv = (_Float16)nons[d0];

        h16x2 q[4];
#pragma unroll
        for (int jp = 0; jp < 4; ++jp) {
            h16x2 qq;
#pragma unroll
            for (int e = 0; e < 2; ++e) {
                const int t   = tc * CRv_ + kbase + 2 * jp + e;
                const int tcl = (t < T_) ? t : (T_ - 1);
                _Float16 us = vrow[tcl * D_ + d0];
                qq[e] = (t < T_) ? us : nv;
            }
            q[jp] = qq;
        }
        h16x8 af = packH4(q[0], q[1], q[2], q[3]);

        f32x4 acc[4];
#pragma unroll
        for (int cn = 0; cn < 4; ++cn)
            acc[cn] = __builtin_amdgcn_mfma_f32_16x16x32_f16(bfragA[cn], af, ci[cn], 0, 0, 0);

        h16x2 pc0 = hsplat(0.f), pc1 = hsplat(0.f);
#pragma unroll
        for (int cn = 0; cn < 4; ++cn) {
            h16x2 a01 = cvt_pk(acc[cn][0], acc[cn][1]);
            h16x2 a23 = cvt_pk(acc[cn][2], acc[cn][3]);
            gelu_w2_pk(a01, w2pk[2 * cn + 0], pc0);
            gelu_w2_pk(a23, w2pk[2 * cn + 1], pc1);
        }
        float pr = ((float)pc0[0] + (float)pc0[1]) + ((float)pc1[0] + (float)pc1[1]);
        pr += __shfl_xor(pr, 16);
        pr += __shfl_xor(pr, 32);

        if (g == 0)
            hbuf[(long)((b * CL_ + cl) * 16 + tc) * D_ + d0] = pr + b2s;
    }
}

// ---- Stage 3: C(512x1024) = H @ projW^T + bias (fp32 tiled GEMM)
__global__ __launch_bounds__(256) void k_proj(
    const float* __restrict__ H, const float* __restrict__ Wp,
    const float* __restrict__ bias, float* __restrict__ Cout)
{
    constexpr int BM = 32, BN = 64, BK = 32, K = 1024, NCOLB = OUT_ / BN; // 16
    __shared__ float Ht[BM][BK + 1];
    __shared__ float Wt[BN][BK + 1];

    const int bn = blockIdx.x % NCOLB;
    const int bm = blockIdx.x / NCOLB;
    const int tid = threadIdx.x;
    const int tx = tid & 15;
    const int ty = tid >> 4;
    const int lr = tid >> 3;
    const int lc = (tid & 7) << 2;

    float acc[2][4] = {};

    for (int k0 = 0; k0 < K; k0 += BK) {
        float4 hv  = *(const float4*)(H  + (long)(bm * BM + lr) * K + k0 + lc);
        float4 w0  = *(const float4*)(Wp + (long)(bn * BN + lr) * K + k0 + lc);
        float4 w1v = *(const float4*)(Wp + (long)(bn * BN + 32 + lr) * K + k0 + lc);
        Ht[lr][lc + 0] = hv.x;  Ht[lr][lc + 1] = hv.y;  Ht[lr][lc + 2] = hv.z;  Ht[lr][lc + 3] = hv.w;
        Wt[lr][lc + 0] = w0.x;  Wt[lr][lc + 1] = w0.y;  Wt[lr][lc + 2] = w0.z;  Wt[lr][lc + 3] = w0.w;
        Wt[32 + lr][lc + 0] = w1v.x; Wt[32 + lr][lc + 1] = w1v.y; Wt[32 + lr][lc + 2] = w1v.z; Wt[32 + lr][lc + 3] = w1v.w;
        __syncthreads();

#pragma unroll
        for (int kk = 0; kk < BK; ++kk) {
            float va0 = Ht[ty * 2 + 0][kk];
            float va1 = Ht[ty * 2 + 1][kk];
            float vb0 = Wt[tx * 4 + 0][kk];
            float vb1 = Wt[tx * 4 + 1][kk];
            float vb2 = Wt[tx * 4 + 2][kk];
            float vb3 = Wt[tx * 4 + 3][kk];
            acc[0][0] = fmaf(va0, vb0, acc[0][0]);
            acc[0][1] = fmaf(va0, vb1, acc[0][1]);
            acc[0][2] = fmaf(va0, vb2, acc[0][2]);
            acc[0][3] = fmaf(va0, vb3, acc[0][3]);
            acc[1][0] = fmaf(va1, vb0, acc[1][0]);
            acc[1][1] = fmaf(va1, vb1, acc[1][1]);
            acc[1][2] = fmaf(va1, vb2, acc[1][2]);
            acc[1][3] = fmaf(va1, vb3, acc[1][3]);
        }
        __syncthreads();
    }

#pragma unroll
    for (int i = 0; i < 2; ++i) {
#pragma unroll
        for (int jj = 0; jj < 4; ++jj) {
            int r = bm * BM + ty * 2 + i;
            int c = bn * BN + tx * 4 + jj;
            Cout[(long)r * OUT_ + c] = acc[i][jj] + bias[c];
        }
    }
}

extern "C" void kernel_launch(void* const* d_in, const int* in_sizes, int n_in,
                              void* d_out, int out_size, void* d_ws, size_t ws_size,
                              hipStream_t stream) {
    const float* mem    = (const float*)d_in[0];
    const float* dim_pe = (const float*)d_in[2];
    const float* vW1    = (const float*)d_in[3];
    const float* vb1    = (const float*)d_in[4];
    const float* vW2    = (const float*)d_in[5];
    const float* vb2    = (const float*)d_in[6];
    const float* hW1    = (const float*)d_in[7];
    const float* hb1    = (const float*)d_in[8];
    const float* hW2    = (const float*)d_in[9];
    const float* hb2    = (const float*)d_in[10];
    const float* projW  = (const float*)d_in[11];
    const float* projb  = (const float*)d_in[12];
    float* out = (float*)d_out;

    _Float16* vbuf = (_Float16*)d_ws;                                   // f16, 16 MB
    float* hbuf = (float*)((char*)d_ws + (size_t)B_ * CL_ * T_ * D_ * sizeof(_Float16));

    k_stage1<<<B_ * CL_ * NTCH_ * 4, 256, 0, stream>>>(mem, dim_pe, vW1, vb1, vW2, vb2, vbuf);
    k_stage2<<<B_ * CL_ * 16 * 4, 256, 0, stream>>>(vbuf, mem, hW1, hb1, hW2, hb2, hbuf);
    k_proj<<<(512 / 32) * (OUT_ / 64), 256, 0, stream>>>(hbuf, projW, projb, out);
}

// Round 8
// 226.189 us; speedup vs baseline: 1.5205x; 1.0195x over previous
//
#include <hip/hip_runtime.h>
#include <hip/hip_bf16.h>

#define B_ 2
#define L_ 256
#define T_ 250
#define D_ 1024
#define NH_ 16
#define DH_ 64
#define CRv_ 16
#define HID_ 64
#define CL_ 16
#define OUT_ 1024
#define MEMROWS_ 64001L
#define TCH_ 25
#define NTCH_ (T_ / TCH_)   // 10

#define AS1 __attribute__((address_space(1)))
#define AS3 __attribute__((address_space(3)))

typedef __attribute__((ext_vector_type(2))) _Float16 h16x2;
typedef __attribute__((ext_vector_type(8))) _Float16 h16x8;
typedef __attribute__((ext_vector_type(4))) float f32x4;

__device__ __forceinline__ h16x2 cvt_pk(float lo, float hi) {
    return __builtin_bit_cast(h16x2, __builtin_amdgcn_cvt_pkrtz(lo, hi));
}

struct H4 { h16x2 a, b, c, d; };
__device__ __forceinline__ h16x8 packH4(h16x2 a, h16x2 b, h16x2 c, h16x2 d) {
    H4 h{a, b, c, d};
    return __builtin_bit_cast(h16x8, h);
}
__device__ __forceinline__ h16x2 hsplat(float x) {
    _Float16 h = (_Float16)x;
    h16x2 v; v[0] = h; v[1] = h;
    return v;
}

// Packed-f16 gelu * w2 accumulate. E(t') = t'*P~(t'^2), t' = clamp(x/2, +-1.75).
__device__ __forceinline__ void gelu_w2_pk(h16x2 a, h16x2 w, h16x2& pacc) {
    const h16x2 C0 = hsplat(1.5957600f);
    const h16x2 C1 = hsplat(-1.0445624f);
    const h16x2 C2 = hsplat(0.5417632f);
    const h16x2 C3 = hsplat(-0.15817472f);
    const h16x2 C4 = hsplat(0.018604288f);
    h16x2 ha = a * hsplat(0.5f);
    h16x2 t  = __builtin_elementwise_min(__builtin_elementwise_max(ha, hsplat(-1.75f)), hsplat(1.75f));
    h16x2 s  = t * t;
    h16x2 p  = C4 * s + C3;
    p = p * s + C2;
    p = p * s + C1;
    p = p * s + C0;
    h16x2 e  = t * p;
    h16x2 g  = ha * e + ha;
    pacc = g * w + pacc;
}

#define WAITV(n) asm volatile("s_waitcnt vmcnt(" #n ")" ::: "memory")
#define MEMBAR() asm volatile("" ::: "memory")

// ---- Stage 1: v-MLP. One wave = one head. LDS-staged x-tile, dbuf over t,
// pe@W1 folded into the MFMA's upper-K half (A upper = W1 dup, B upper = pe f16).
__global__ __launch_bounds__(256) void k_stage1(
    const float* __restrict__ mem, const float* __restrict__ dim_pe,
    const float* __restrict__ W1, const float* __restrict__ b1,
    const float* __restrict__ W2, const float* __restrict__ b2,
    _Float16* __restrict__ vbuf)
{
    __shared__ float stage[4][2][1024];   // [wave][buf][16 rows x 64 cols]

    const int blk = blockIdx.x;                 // ((b*CL + cl)*NTCH + tch)*4 + nhg
    const int nhg  = blk & 3;
    const int tch  = (blk >> 2) % NTCH_;
    const int rest = (blk >> 2) / NTCH_;
    const int cl   = rest & (CL_ - 1);
    const int b    = rest >> 4;
    const int lane = threadIdx.x & 63;
    const int wv   = threadIdx.x >> 6;
    const int nh   = nhg * 4 + wv;
    const int g    = lane >> 4;                 // k-group; also output f-subrow group
    const int fl   = lane & 15;
    const int kbase = (8 * g) & 15;             // g0->cr0-7, g1->cr8-15, g2->cr0-7, g3->cr8-15
    const bool klive = (g < 2);                 // lower-K lanes carry x; upper-K carry pe

    const float* membase = mem + (long)b * MEMROWS_ * D_;
    _Float16* vrow = vbuf + (long)(b * CL_ + cl) * T_ * D_;
    const int t0 = tch * TCH_;

    // pe fragments (f16, loop-invariant B upper-K content)
    h16x8 peq[4];
#pragma unroll
    for (int ct = 0; ct < 4; ++ct) {
        const int d0 = nh * DH_ + ct * 16 + fl;
        float p0 = dim_pe[(kbase + 0) * D_ + d0];
        float p1 = dim_pe[(kbase + 1) * D_ + d0];
        float p2 = dim_pe[(kbase + 2) * D_ + d0];
        float p3 = dim_pe[(kbase + 3) * D_ + d0];
        float p4 = dim_pe[(kbase + 4) * D_ + d0];
        float p5 = dim_pe[(kbase + 5) * D_ + d0];
        float p6 = dim_pe[(kbase + 6) * D_ + d0];
        float p7 = dim_pe[(kbase + 7) * D_ + d0];
        peq[ct] = packH4(cvt_pk(p0, p1), cvt_pk(p2, p3), cvt_pk(p4, p5), cvt_pk(p6, p7));
    }

    // W1^T A-fragments: BOTH K-halves hold W1 (upper pairs with pe in B).
    h16x8 bfragA[4];
    f32x4 ci[4];
    h16x2 w2pk[8];
#pragma unroll
    for (int cn = 0; cn < 4; ++cn) {
        h16x2 q[4];
#pragma unroll
        for (int jp = 0; jp < 4; ++jp) {
            float w0 = W1[(nh * CRv_ + kbase + 2 * jp + 0) * HID_ + cn * 16 + fl];
            float w1 = W1[(nh * CRv_ + kbase + 2 * jp + 1) * HID_ + cn * 16 + fl];
            h16x2 qq; qq[0] = (_Float16)w0; qq[1] = (_Float16)w1;
            q[jp] = qq;
        }
        bfragA[cn] = packH4(q[0], q[1], q[2], q[3]);
#pragma unroll
        for (int r = 0; r < 4; ++r) ci[cn][r] = b1[nh * HID_ + cn * 16 + 4 * g + r];
        h16x2 wlo; wlo[0] = (_Float16)W2[nh * HID_ + cn * 16 + 4 * g + 0];
                   wlo[1] = (_Float16)W2[nh * HID_ + cn * 16 + 4 * g + 1];
        h16x2 whi; whi[0] = (_Float16)W2[nh * HID_ + cn * 16 + 4 * g + 2];
                   whi[1] = (_Float16)W2[nh * HID_ + cn * 16 + 4 * g + 3];
        w2pk[2 * cn + 0] = wlo;
        w2pk[2 * cn + 1] = whi;
    }
    const float b2s = b2[nh];

    // Staging pointers: instruction i loads rows i*4 + lane/16, col-quad lane%16.
    const int srow = lane >> 4;
    const int scol = (lane & 15) * 4;
    const float* gpa = membase + ((size_t)(cl * CRv_ +  0 + srow) * T_ + t0) * D_ + nh * DH_ + scol;
    const float* gpb = membase + ((size_t)(cl * CRv_ +  4 + srow) * T_ + t0) * D_ + nh * DH_ + scol;
    const float* gpc = membase + ((size_t)(cl * CRv_ +  8 + srow) * T_ + t0) * D_ + nh * DH_ + scol;
    const float* gpd = membase + ((size_t)(cl * CRv_ + 12 + srow) * T_ + t0) * D_ + nh * DH_ + scol;

#define ISSUE(c) do { \
    __builtin_amdgcn_global_load_lds((const AS1 void*)gpa, (AS3 void*)(&stage[wv][(c)][0 * 256]), 16, 0, 0); \
    __builtin_amdgcn_global_load_lds((const AS1 void*)gpb, (AS3 void*)(&stage[wv][(c)][1 * 256]), 16, 0, 0); \
    __builtin_amdgcn_global_load_lds((const AS1 void*)gpc, (AS3 void*)(&stage[wv][(c)][2 * 256]), 16, 0, 0); \
    __builtin_amdgcn_global_load_lds((const AS1 void*)gpd, (AS3 void*)(&stage[wv][(c)][3 * 256]), 16, 0, 0); \
    gpa += D_; gpb += D_; gpc += D_; gpd += D_; } while (0)

    ISSUE(0);                                   // prefetch t0
    int cur = 0;

    for (int tt = 0; tt < TCH_; ++tt) {
        if (tt + 1 < TCH_) ISSUE(cur ^ 1);      // prefetch t+1
        if (tt == 0)            WAITV(4);
        else if (tt == TCH_-1)  WAITV(1);
        else                    WAITV(5);

        const float* bufp = &stage[wv][cur][0];
        _Float16 vkeep = (_Float16)0.f;

#pragma unroll
        for (int ct = 0; ct < 4; ++ct) {
            float a0 = bufp[(kbase + 0) * 64 + ct * 16 + fl];
            float a1 = bufp[(kbase + 1) * 64 + ct * 16 + fl];
            float a2 = bufp[(kbase + 2) * 64 + ct * 16 + fl];
            float a3 = bufp[(kbase + 3) * 64 + ct * 16 + fl];
            float a4 = bufp[(kbase + 4) * 64 + ct * 16 + fl];
            float a5 = bufp[(kbase + 5) * 64 + ct * 16 + fl];
            float a6 = bufp[(kbase + 6) * 64 + ct * 16 + fl];
            float a7 = bufp[(kbase + 7) * 64 + ct * 16 + fl];
            h16x8 xq = packH4(cvt_pk(a0, a1), cvt_pk(a2, a3), cvt_pk(a4, a5), cvt_pk(a6, a7));
            h16x8 af = klive ? xq : peq[ct];    // lower-K lanes: x; upper-K lanes: pe

            f32x4 acc[4];
#pragma unroll
            for (int cn = 0; cn < 4; ++cn)
                acc[cn] = __builtin_amdgcn_mfma_f32_16x16x32_f16(bfragA[cn], af, ci[cn], 0, 0, 0);

            h16x2 pc0 = hsplat(0.f), pc1 = hsplat(0.f);
#pragma unroll
            for (int cn = 0; cn < 4; ++cn) {
                h16x2 a01 = cvt_pk(acc[cn][0], acc[cn][1]);
                h16x2 a23 = cvt_pk(acc[cn][2], acc[cn][3]);
                gelu_w2_pk(a01, w2pk[2 * cn + 0], pc0);
                gelu_w2_pk(a23, w2pk[2 * cn + 1], pc1);
            }
            float pr = ((float)pc0[0] + (float)pc0[1]) + ((float)pc1[0] + (float)pc1[1]);
            pr += __shfl_xor(pr, 16);
            pr += __shfl_xor(pr, 32);           // all lanes hold out(d = ct*16+fl)

            if (g == ct) vkeep = (_Float16)(pr + b2s);
        }
        // one contiguous 2B/lane store: lane (g,fl) owns d = g*16+fl
        vrow[(size_t)(t0 + tt) * D_ + nh * DH_ + g * 16 + fl] = vkeep;
        MEMBAR();                                // pin store before next ISSUE
        cur ^= 1;
    }
#undef ISSUE
}

// ---- Stage 2: h-MLP over t = tc*16+cr (pad rows -> nonsense).
__global__ __launch_bounds__(256) void k_stage2(
    const _Float16* __restrict__ vbuf, const float* __restrict__ mem,
    const float* __restrict__ W1, const float* __restrict__ b1,
    const float* __restrict__ W2, const float* __restrict__ b2,
    float* __restrict__ hbuf)
{
    const int blk = blockIdx.x;                // ((b*CL + cl)*16 + tc)*4 + nhg
    const int nhg = blk & 3;
    const int tc  = (blk >> 2) & 15;
    const int cl  = (blk >> 6) & 15;
    const int b   = blk >> 10;
    const int lane = threadIdx.x & 63;
    const int wv   = threadIdx.x >> 6;
    const int nh   = nhg * 4 + wv;
    const int g    = lane >> 4;
    const int fl   = lane & 15;
    const int kbase = (8 * g) & 15;
    const bool klive = (g < 2);

    const _Float16* vrow = vbuf + (long)(b * CL_ + cl) * T_ * D_;
    const float* nons = mem + ((long)b * MEMROWS_ + (long)L_ * T_) * D_;

    h16x8 bfragA[4];
    f32x4 ci[4];
    h16x2 w2pk[8];
#pragma unroll
    for (int cn = 0; cn < 4; ++cn) {
        h16x2 q[4];
#pragma unroll
        for (int jp = 0; jp < 4; ++jp) {
            float w0 = W1[(nh * CRv_ + kbase + 2 * jp + 0) * HID_ + cn * 16 + fl];
            float w1 = W1[(nh * CRv_ + kbase + 2 * jp + 1) * HID_ + cn * 16 + fl];
            h16x2 qq; qq[0] = klive ? (_Float16)w0 : (_Float16)0.f;
                      qq[1] = klive ? (_Float16)w1 : (_Float16)0.f;
            q[jp] = qq;
        }
        bfragA[cn] = packH4(q[0], q[1], q[2], q[3]);
#pragma unroll
        for (int r = 0; r < 4; ++r) ci[cn][r] = b1[nh * HID_ + cn * 16 + 4 * g + r];
        h16x2 wlo; wlo[0] = (_Float16)W2[nh * HID_ + cn * 16 + 4 * g + 0];
                   wlo[1] = (_Float16)W2[nh * HID_ + cn * 16 + 4 * g + 1];
        h16x2 whi; whi[0] = (_Float16)W2[nh * HID_ + cn * 16 + 4 * g + 2];
                   whi[1] = (_Float16)W2[nh * HID_ + cn * 16 + 4 * g + 3];
        w2pk[2 * cn + 0] = wlo;
        w2pk[2 * cn + 1] = whi;
    }
    const float b2s = b2[nh];

#pragma unroll 1
    for (int ct = 0; ct < 4; ++ct) {
        const int d0 = nh * DH_ + ct * 16 + fl;
        const _Float16 nv = (_Float16)nons[d0];

        h16x2 q[4];
#pragma unroll
        for (int jp = 0; jp < 4; ++jp) {
            h16x2 qq;
#pragma unroll
            for (int e = 0; e < 2; ++e) {
                const int t   = tc * CRv_ + kbase + 2 * jp + e;
                const int tcl = (t < T_) ? t : (T_ - 1);
                _Float16 us = vrow[tcl * D_ + d0];
                qq[e] = (t < T_) ? us : nv;
            }
            q[jp] = qq;
        }
        h16x8 af = packH4(q[0], q[1], q[2], q[3]);

        f32x4 acc[4];
#pragma unroll
        for (int cn = 0; cn < 4; ++cn)
            acc[cn] = __builtin_amdgcn_mfma_f32_16x16x32_f16(bfragA[cn], af, ci[cn], 0, 0, 0);

        h16x2 pc0 = hsplat(0.f), pc1 = hsplat(0.f);
#pragma unroll
        for (int cn = 0; cn < 4; ++cn) {
            h16x2 a01 = cvt_pk(acc[cn][0], acc[cn][1]);
            h16x2 a23 = cvt_pk(acc[cn][2], acc[cn][3]);
            gelu_w2_pk(a01, w2pk[2 * cn + 0], pc0);
            gelu_w2_pk(a23, w2pk[2 * cn + 1], pc1);
        }
        float pr = ((float)pc0[0] + (float)pc0[1]) + ((float)pc1[0] + (float)pc1[1]);
        pr += __shfl_xor(pr, 16);
        pr += __shfl_xor(pr, 32);

        if (g == 0)
            hbuf[(long)((b * CL_ + cl) * 16 + tc) * D_ + d0] = pr + b2s;
    }
}

// ---- Stage 3: C(512x1024) = H @ projW^T + bias (fp32 tiled GEMM)
__global__ __launch_bounds__(256) void k_proj(
    const float* __restrict__ H, const float* __restrict__ Wp,
    const float* __restrict__ bias, float* __restrict__ Cout)
{
    constexpr int BM = 32, BN = 64, BK = 32, K = 1024, NCOLB = OUT_ / BN; // 16
    __shared__ float Ht[BM][BK + 1];
    __shared__ float Wt[BN][BK + 1];

    const int bn = blockIdx.x % NCOLB;
    const int bm = blockIdx.x / NCOLB;
    const int tid = threadIdx.x;
    const int tx = tid & 15;
    const int ty = tid >> 4;
    const int lr = tid >> 3;
    const int lc = (tid & 7) << 2;

    float acc[2][4] = {};

    for (int k0 = 0; k0 < K; k0 += BK) {
        float4 hv  = *(const float4*)(H  + (long)(bm * BM + lr) * K + k0 + lc);
        float4 w0  = *(const float4*)(Wp + (long)(bn * BN + lr) * K + k0 + lc);
        float4 w1v = *(const float4*)(Wp + (long)(bn * BN + 32 + lr) * K + k0 + lc);
        Ht[lr][lc + 0] = hv.x;  Ht[lr][lc + 1] = hv.y;  Ht[lr][lc + 2] = hv.z;  Ht[lr][lc + 3] = hv.w;
        Wt[lr][lc + 0] = w0.x;  Wt[lr][lc + 1] = w0.y;  Wt[lr][lc + 2] = w0.z;  Wt[lr][lc + 3] = w0.w;
        Wt[32 + lr][lc + 0] = w1v.x; Wt[32 + lr][lc + 1] = w1v.y; Wt[32 + lr][lc + 2] = w1v.z; Wt[32 + lr][lc + 3] = w1v.w;
        __syncthreads();

#pragma unroll
        for (int kk = 0; kk < BK; ++kk) {
            float va0 = Ht[ty * 2 + 0][kk];
            float va1 = Ht[ty * 2 + 1][kk];
            float vb0 = Wt[tx * 4 + 0][kk];
            float vb1 = Wt[tx * 4 + 1][kk];
            float vb2 = Wt[tx * 4 + 2][kk];
            float vb3 = Wt[tx * 4 + 3][kk];
            acc[0][0] = fmaf(va0, vb0, acc[0][0]);
            acc[0][1] = fmaf(va0, vb1, acc[0][1]);
            acc[0][2] = fmaf(va0, vb2, acc[0][2]);
            acc[0][3] = fmaf(va0, vb3, acc[0][3]);
            acc[1][0] = fmaf(va1, vb0, acc[1][0]);
            acc[1][1] = fmaf(va1, vb1, acc[1][1]);
            acc[1][2] = fmaf(va1, vb2, acc[1][2]);
            acc[1][3] = fmaf(va1, vb3, acc[1][3]);
        }
        __syncthreads();
    }

#pragma unroll
    for (int i = 0; i < 2; ++i) {
#pragma unroll
        for (int jj = 0; jj < 4; ++jj) {
            int r = bm * BM + ty * 2 + i;
            int c = bn * BN + tx * 4 + jj;
            Cout[(long)r * OUT_ + c] = acc[i][jj] + bias[c];
        }
    }
}

extern "C" void kernel_launch(void* const* d_in, const int* in_sizes, int n_in,
                              void* d_out, int out_size, void* d_ws, size_t ws_size,
                              hipStream_t stream) {
    const float* mem    = (const float*)d_in[0];
    const float* dim_pe = (const float*)d_in[2];
    const float* vW1    = (const float*)d_in[3];
    const float* vb1    = (const float*)d_in[4];
    const float* vW2    = (const float*)d_in[5];
    const float* vb2    = (const float*)d_in[6];
    const float* hW1    = (const float*)d_in[7];
    const float* hb1    = (const float*)d_in[8];
    const float* hW2    = (const float*)d_in[9];
    const float* hb2    = (const float*)d_in[10];
    const float* projW  = (const float*)d_in[11];
    const float* projb  = (const float*)d_in[12];
    float* out = (float*)d_out;

    _Float16* vbuf = (_Float16*)d_ws;                                   // f16, 16 MB
    float* hbuf = (float*)((char*)d_ws + (size_t)B_ * CL_ * T_ * D_ * sizeof(_Float16));

    k_stage1<<<B_ * CL_ * NTCH_ * 4, 256, 0, stream>>>(mem, dim_pe, vW1, vb1, vW2, vb2, vbuf);
    k_stage2<<<B_ * CL_ * 16 * 4, 256, 0, stream>>>(vbuf, mem, hW1, hb1, hW2, hb2, hbuf);
    k_proj<<<(512 / 32) * (OUT_ / 64), 256, 0, stream>>>(hbuf, projW, projb, out);
}

// Round 9
// 221.049 us; speedup vs baseline: 1.5558x; 1.0233x over previous
//
#include <hip/hip_runtime.h>
#include <hip/hip_bf16.h>

#define B_ 2
#define L_ 256
#define T_ 250
#define D_ 1024
#define NH_ 16
#define DH_ 64
#define CRv_ 16
#define HID_ 64
#define CL_ 16
#define OUT_ 1024
#define MEMROWS_ 64001L
#define TCH_ 25
#define NTCH_ (T_ / TCH_)   // 10

#define AS1 __attribute__((address_space(1)))
#define AS3 __attribute__((address_space(3)))

typedef __attribute__((ext_vector_type(2))) _Float16 h16x2;
typedef __attribute__((ext_vector_type(8))) _Float16 h16x8;
typedef __attribute__((ext_vector_type(4))) float f32x4;

__device__ __forceinline__ h16x2 cvt_pk(float lo, float hi) {
    return __builtin_bit_cast(h16x2, __builtin_amdgcn_cvt_pkrtz(lo, hi));
}

struct H4 { h16x2 a, b, c, d; };
__device__ __forceinline__ h16x8 packH4(h16x2 a, h16x2 b, h16x2 c, h16x2 d) {
    H4 h{a, b, c, d};
    return __builtin_bit_cast(h16x8, h);
}
__device__ __forceinline__ h16x2 hsplat(float x) {
    _Float16 h = (_Float16)x;
    h16x2 v; v[0] = h; v[1] = h;
    return v;
}
__device__ __forceinline__ unsigned pkadd(unsigned a, unsigned b) {
    h16x2 r = __builtin_bit_cast(h16x2, a) + __builtin_bit_cast(h16x2, b);
    return __builtin_bit_cast(unsigned, r);
}

// Packed-f16 gelu * w2 accumulate. E(t') = t'*P~(t'^2), t' = clamp(x/2, +-1.75).
__device__ __forceinline__ void gelu_w2_pk(h16x2 a, h16x2 w, h16x2& pacc) {
    const h16x2 C0 = hsplat(1.5957600f);
    const h16x2 C1 = hsplat(-1.0445624f);
    const h16x2 C2 = hsplat(0.5417632f);
    const h16x2 C3 = hsplat(-0.15817472f);
    const h16x2 C4 = hsplat(0.018604288f);
    h16x2 ha = a * hsplat(0.5f);
    h16x2 t  = __builtin_elementwise_min(__builtin_elementwise_max(ha, hsplat(-1.75f)), hsplat(1.75f));
    h16x2 s  = t * t;
    h16x2 p  = C4 * s + C3;
    p = p * s + C2;
    p = p * s + C1;
    p = p * s + C0;
    h16x2 e  = t * p;
    h16x2 g  = ha * e + ha;
    pacc = g * w + pacc;
}

#define WAITV(n) asm volatile("s_waitcnt vmcnt(" #n ")" ::: "memory")
#define MEMBAR() asm volatile("" ::: "memory")

// ---- Stage 1: v-MLP. One wave = one head. Triple-buffered LDS x-tile
// (16cr x 64d f32), prefetch distance 2, exact counted vmcnt.
__global__ __launch_bounds__(256) void k_stage1(
    const float* __restrict__ mem, const float* __restrict__ dim_pe,
    const float* __restrict__ W1, const float* __restrict__ b1,
    const float* __restrict__ W2, const float* __restrict__ b2,
    _Float16* __restrict__ vbuf)
{
    __shared__ float stage[4][3][1024];   // [wave][buf][16 rows x 64 cols]  48 KB

    const int blk = blockIdx.x;                 // ((b*CL + cl)*NTCH + tch)*4 + nhg
    const int nhg  = blk & 3;
    const int tch  = (blk >> 2) % NTCH_;
    const int rest = (blk >> 2) / NTCH_;
    const int cl   = rest & (CL_ - 1);
    const int b    = rest >> 4;
    const int lane = threadIdx.x & 63;
    const int wv   = threadIdx.x >> 6;
    const int nh   = nhg * 4 + wv;
    const int g    = lane >> 4;                 // k-group; also output ct owner
    const int fl   = lane & 15;
    const int kbase = (8 * g) & 15;             // g0->cr0-7, g1->cr8-15, dup for g2/g3
    const bool klive = (g < 2);                 // lower-K lanes carry x; upper-K carry pe

    const float* membase = mem + (long)b * MEMROWS_ * D_;
    _Float16* vrow = vbuf + (long)(b * CL_ + cl) * T_ * D_;
    const int t0 = tch * TCH_;

    // pe fragments (f16, loop-invariant B upper-K content)
    h16x8 peq[4];
#pragma unroll
    for (int ct = 0; ct < 4; ++ct) {
        const int d0 = nh * DH_ + ct * 16 + fl;
        float p0 = dim_pe[(kbase + 0) * D_ + d0];
        float p1 = dim_pe[(kbase + 1) * D_ + d0];
        float p2 = dim_pe[(kbase + 2) * D_ + d0];
        float p3 = dim_pe[(kbase + 3) * D_ + d0];
        float p4 = dim_pe[(kbase + 4) * D_ + d0];
        float p5 = dim_pe[(kbase + 5) * D_ + d0];
        float p6 = dim_pe[(kbase + 6) * D_ + d0];
        float p7 = dim_pe[(kbase + 7) * D_ + d0];
        peq[ct] = packH4(cvt_pk(p0, p1), cvt_pk(p2, p3), cvt_pk(p4, p5), cvt_pk(p6, p7));
    }

    // W1^T A-fragments: BOTH K-halves hold W1 (upper pairs with pe in B).
    h16x8 bfragA[4];
    f32x4 ci[4];
    h16x2 w2pk[8];
#pragma unroll
    for (int cn = 0; cn < 4; ++cn) {
        h16x2 q[4];
#pragma unroll
        for (int jp = 0; jp < 4; ++jp) {
            float w0 = W1[(nh * CRv_ + kbase + 2 * jp + 0) * HID_ + cn * 16 + fl];
            float w1 = W1[(nh * CRv_ + kbase + 2 * jp + 1) * HID_ + cn * 16 + fl];
            h16x2 qq; qq[0] = (_Float16)w0; qq[1] = (_Float16)w1;
            q[jp] = qq;
        }
        bfragA[cn] = packH4(q[0], q[1], q[2], q[3]);
#pragma unroll
        for (int r = 0; r < 4; ++r) ci[cn][r] = b1[nh * HID_ + cn * 16 + 4 * g + r];
        h16x2 wlo; wlo[0] = (_Float16)W2[nh * HID_ + cn * 16 + 4 * g + 0];
                   wlo[1] = (_Float16)W2[nh * HID_ + cn * 16 + 4 * g + 1];
        h16x2 whi; whi[0] = (_Float16)W2[nh * HID_ + cn * 16 + 4 * g + 2];
                   whi[1] = (_Float16)W2[nh * HID_ + cn * 16 + 4 * g + 3];
        w2pk[2 * cn + 0] = wlo;
        w2pk[2 * cn + 1] = whi;
    }
    const float b2s = b2[nh];
    const unsigned b2p = __builtin_bit_cast(unsigned, __builtin_amdgcn_cvt_pkrtz(b2s, b2s));

    // Staging pointers: instruction i loads rows i*4 + lane/16, col-quad lane%16.
    const int srow = lane >> 4;
    const int scol = (lane & 15) * 4;
    const float* gpa = membase + ((size_t)(cl * CRv_ +  0 + srow) * T_ + t0) * D_ + nh * DH_ + scol;
    const float* gpb = membase + ((size_t)(cl * CRv_ +  4 + srow) * T_ + t0) * D_ + nh * DH_ + scol;
    const float* gpc = membase + ((size_t)(cl * CRv_ +  8 + srow) * T_ + t0) * D_ + nh * DH_ + scol;
    const float* gpd = membase + ((size_t)(cl * CRv_ + 12 + srow) * T_ + t0) * D_ + nh * DH_ + scol;

    float* const lbase = &stage[wv][0][0];

#define ISSUE(bi) do { \
    float* lb = lbase + (bi) * 1024; \
    __builtin_amdgcn_global_load_lds((const AS1 void*)gpa, (AS3 void*)(lb + 0 * 256), 16, 0, 0); \
    __builtin_amdgcn_global_load_lds((const AS1 void*)gpb, (AS3 void*)(lb + 1 * 256), 16, 0, 0); \
    __builtin_amdgcn_global_load_lds((const AS1 void*)gpc, (AS3 void*)(lb + 2 * 256), 16, 0, 0); \
    __builtin_amdgcn_global_load_lds((const AS1 void*)gpd, (AS3 void*)(lb + 3 * 256), 16, 0, 0); \
    gpa += D_; gpb += D_; gpc += D_; gpd += D_; } while (0)

    ISSUE(0);                                   // t0
    ISSUE(1);                                   // t1
    int ib0 = 0, ib1 = 1, ib2 = 2;

    for (int tt = 0; tt < TCH_; ++tt) {
        if (tt + 2 < TCH_) ISSUE(ib2);          // prefetch t+2
        // exact counted waits (in-order vmcnt retirement):
        if (tt == 0)              WAITV(8);     // younger than l(t0): l1(4)+l2(4)
        else if (tt == 1)         WAITV(9);     // s0 + l2 + l3
        else if (tt <= TCH_ - 3)  WAITV(10);    // s(t-2)+l(t+1)+s(t-1)+l(t+2)
        else if (tt == TCH_ - 2)  WAITV(6);     // s+l(t+1)+s
        else                      WAITV(2);     // two stores

        const float* bufp = lbase + ib0 * 1024;
        float prl[4];

#pragma unroll
        for (int ct = 0; ct < 4; ++ct) {
            float a0 = bufp[(kbase + 0) * 64 + ct * 16 + fl];
            float a1 = bufp[(kbase + 1) * 64 + ct * 16 + fl];
            float a2 = bufp[(kbase + 2) * 64 + ct * 16 + fl];
            float a3 = bufp[(kbase + 3) * 64 + ct * 16 + fl];
            float a4 = bufp[(kbase + 4) * 64 + ct * 16 + fl];
            float a5 = bufp[(kbase + 5) * 64 + ct * 16 + fl];
            float a6 = bufp[(kbase + 6) * 64 + ct * 16 + fl];
            float a7 = bufp[(kbase + 7) * 64 + ct * 16 + fl];
            h16x8 xq = packH4(cvt_pk(a0, a1), cvt_pk(a2, a3), cvt_pk(a4, a5), cvt_pk(a6, a7));
            h16x8 af = klive ? xq : peq[ct];    // lower-K lanes: x; upper-K lanes: pe

            f32x4 acc[4];
#pragma unroll
            for (int cn = 0; cn < 4; ++cn)
                acc[cn] = __builtin_amdgcn_mfma_f32_16x16x32_f16(bfragA[cn], af, ci[cn], 0, 0, 0);

            h16x2 pc0 = hsplat(0.f), pc1 = hsplat(0.f);
#pragma unroll
            for (int cn = 0; cn < 4; ++cn) {
                h16x2 a01 = cvt_pk(acc[cn][0], acc[cn][1]);
                h16x2 a23 = cvt_pk(acc[cn][2], acc[cn][3]);
                gelu_w2_pk(a01, w2pk[2 * cn + 0], pc0);
                gelu_w2_pk(a23, w2pk[2 * cn + 1], pc1);
            }
            h16x2 P = pc0 + pc1;
            prl[ct] = (float)P[0] + (float)P[1];
        }

        // packed cross-lane reduce: 4 ct partials in 2 u32, xor16 + xor32
        unsigned A = __builtin_bit_cast(unsigned, __builtin_amdgcn_cvt_pkrtz(prl[0], prl[1]));
        unsigned Bp = __builtin_bit_cast(unsigned, __builtin_amdgcn_cvt_pkrtz(prl[2], prl[3]));
        A  = pkadd(A,  (unsigned)__shfl_xor((int)A, 16));
        Bp = pkadd(Bp, (unsigned)__shfl_xor((int)Bp, 16));
        A  = pkadd(A,  (unsigned)__shfl_xor((int)A, 32));
        Bp = pkadd(Bp, (unsigned)__shfl_xor((int)Bp, 32));
        A  = pkadd(A, b2p);
        Bp = pkadd(Bp, b2p);
        unsigned sel = (g < 2) ? A : Bp;        // lane owns ct = g
        unsigned sh  = (g & 1) ? (sel >> 16) : sel;
        vrow[(size_t)(t0 + tt) * D_ + nh * DH_ + g * 16 + fl] =
            __builtin_bit_cast(_Float16, (unsigned short)sh);
        MEMBAR();                                // pin store before next ISSUE
        int tmp = ib0; ib0 = ib1; ib1 = ib2; ib2 = tmp;
    }
#undef ISSUE
}

// ---- Stage 2: h-MLP over t = tc*16+cr (pad rows -> nonsense).
__global__ __launch_bounds__(256) void k_stage2(
    const _Float16* __restrict__ vbuf, const float* __restrict__ mem,
    const float* __restrict__ W1, const float* __restrict__ b1,
    const float* __restrict__ W2, const float* __restrict__ b2,
    float* __restrict__ hbuf)
{
    const int blk = blockIdx.x;                // ((b*CL + cl)*16 + tc)*4 + nhg
    const int nhg = blk & 3;
    const int tc  = (blk >> 2) & 15;
    const int cl  = (blk >> 6) & 15;
    const int b   = blk >> 10;
    const int lane = threadIdx.x & 63;
    const int wv   = threadIdx.x >> 6;
    const int nh   = nhg * 4 + wv;
    const int g    = lane >> 4;
    const int fl   = lane & 15;
    const int kbase = (8 * g) & 15;
    const bool klive = (g < 2);

    const _Float16* vrow = vbuf + (long)(b * CL_ + cl) * T_ * D_;
    const float* nons = mem + ((long)b * MEMROWS_ + (long)L_ * T_) * D_;

    h16x8 bfragA[4];
    f32x4 ci[4];
    h16x2 w2pk[8];
#pragma unroll
    for (int cn = 0; cn < 4; ++cn) {
        h16x2 q[4];
#pragma unroll
        for (int jp = 0; jp < 4; ++jp) {
            float w0 = W1[(nh * CRv_ + kbase + 2 * jp + 0) * HID_ + cn * 16 + fl];
            float w1 = W1[(nh * CRv_ + kbase + 2 * jp + 1) * HID_ + cn * 16 + fl];
            h16x2 qq; qq[0] = klive ? (_Float16)w0 : (_Float16)0.f;
                      qq[1] = klive ? (_Float16)w1 : (_Float16)0.f;
            q[jp] = qq;
        }
        bfragA[cn] = packH4(q[0], q[1], q[2], q[3]);
#pragma unroll
        for (int r = 0; r < 4; ++r) ci[cn][r] = b1[nh * HID_ + cn * 16 + 4 * g + r];
        h16x2 wlo; wlo[0] = (_Float16)W2[nh * HID_ + cn * 16 + 4 * g + 0];
                   wlo[1] = (_Float16)W2[nh * HID_ + cn * 16 + 4 * g + 1];
        h16x2 whi; whi[0] = (_Float16)W2[nh * HID_ + cn * 16 + 4 * g + 2];
                   whi[1] = (_Float16)W2[nh * HID_ + cn * 16 + 4 * g + 3];
        w2pk[2 * cn + 0] = wlo;
        w2pk[2 * cn + 1] = whi;
    }
    const float b2s = b2[nh];

#pragma unroll 1
    for (int ct = 0; ct < 4; ++ct) {
        const int d0 = nh * DH_ + ct * 16 + fl;
        const _Float16 nv = (_Float16)nons[d0];

        h16x2 q[4];
#pragma unroll
        for (int jp = 0; jp < 4; ++jp) {
            h16x2 qq;
#pragma unroll
            for (int e = 0; e < 2; ++e) {
                const int t   = tc * CRv_ + kbase + 2 * jp + e;
                const int tcl = (t < T_) ? t : (T_ - 1);
                _Float16 us = vrow[tcl * D_ + d0];
                qq[e] = (t < T_) ? us : nv;
            }
            q[jp] = qq;
        }
        h16x8 af = packH4(q[0], q[1], q[2], q[3]);

        f32x4 acc[4];
#pragma unroll
        for (int cn = 0; cn < 4; ++cn)
            acc[cn] = __builtin_amdgcn_mfma_f32_16x16x32_f16(bfragA[cn], af, ci[cn], 0, 0, 0);

        h16x2 pc0 = hsplat(0.f), pc1 = hsplat(0.f);
#pragma unroll
        for (int cn = 0; cn < 4; ++cn) {
            h16x2 a01 = cvt_pk(acc[cn][0], acc[cn][1]);
            h16x2 a23 = cvt_pk(acc[cn][2], acc[cn][3]);
            gelu_w2_pk(a01, w2pk[2 * cn + 0], pc0);
            gelu_w2_pk(a23, w2pk[2 * cn + 1], pc1);
        }
        float pr = ((float)pc0[0] + (float)pc0[1]) + ((float)pc1[0] + (float)pc1[1]);
        pr += __shfl_xor(pr, 16);
        pr += __shfl_xor(pr, 32);

        if (g == 0)
            hbuf[(long)((b * CL_ + cl) * 16 + tc) * D_ + d0] = pr + b2s;
    }
}

// ---- Stage 3: C(512x1024) = H @ projW^T + bias (fp32 tiled GEMM)
__global__ __launch_bounds__(256) void k_proj(
    const float* __restrict__ H, const float* __restrict__ Wp,
    const float* __restrict__ bias, float* __restrict__ Cout)
{
    constexpr int BM = 32, BN = 64, BK = 32, K = 1024, NCOLB = OUT_ / BN; // 16
    __shared__ float Ht[BM][BK + 1];
    __shared__ float Wt[BN][BK + 1];

    const int bn = blockIdx.x % NCOLB;
    const int bm = blockIdx.x / NCOLB;
    const int tid = threadIdx.x;
    const int tx = tid & 15;
    const int ty = tid >> 4;
    const int lr = tid >> 3;
    const int lc = (tid & 7) << 2;

    float acc[2][4] = {};

    for (int k0 = 0; k0 < K; k0 += BK) {
        float4 hv  = *(const float4*)(H  + (long)(bm * BM + lr) * K + k0 + lc);
        float4 w0  = *(const float4*)(Wp + (long)(bn * BN + lr) * K + k0 + lc);
        float4 w1v = *(const float4*)(Wp + (long)(bn * BN + 32 + lr) * K + k0 + lc);
        Ht[lr][lc + 0] = hv.x;  Ht[lr][lc + 1] = hv.y;  Ht[lr][lc + 2] = hv.z;  Ht[lr][lc + 3] = hv.w;
        Wt[lr][lc + 0] = w0.x;  Wt[lr][lc + 1] = w0.y;  Wt[lr][lc + 2] = w0.z;  Wt[lr][lc + 3] = w0.w;
        Wt[32 + lr][lc + 0] = w1v.x; Wt[32 + lr][lc + 1] = w1v.y; Wt[32 + lr][lc + 2] = w1v.z; Wt[32 + lr][lc + 3] = w1v.w;
        __syncthreads();

#pragma unroll
        for (int kk = 0; kk < BK; ++kk) {
            float va0 = Ht[ty * 2 + 0][kk];
            float va1 = Ht[ty * 2 + 1][kk];
            float vb0 = Wt[tx * 4 + 0][kk];
            float vb1 = Wt[tx * 4 + 1][kk];
            float vb2 = Wt[tx * 4 + 2][kk];
            float vb3 = Wt[tx * 4 + 3][kk];
            acc[0][0] = fmaf(va0, vb0, acc[0][0]);
            acc[0][1] = fmaf(va0, vb1, acc[0][1]);
            acc[0][2] = fmaf(va0, vb2, acc[0][2]);
            acc[0][3] = fmaf(va0, vb3, acc[0][3]);
            acc[1][0] = fmaf(va1, vb0, acc[1][0]);
            acc[1][1] = fmaf(va1, vb1, acc[1][1]);
            acc[1][2] = fmaf(va1, vb2, acc[1][2]);
            acc[1][3] = fmaf(va1, vb3, acc[1][3]);
        }
        __syncthreads();
    }

#pragma unroll
    for (int i = 0; i < 2; ++i) {
#pragma unroll
        for (int jj = 0; jj < 4; ++jj) {
            int r = bm * BM + ty * 2 + i;
            int c = bn * BN + tx * 4 + jj;
            Cout[(long)r * OUT_ + c] = acc[i][jj] + bias[c];
        }
    }
}

extern "C" void kernel_launch(void* const* d_in, const int* in_sizes, int n_in,
                              void* d_out, int out_size, void* d_ws, size_t ws_size,
                              hipStream_t stream) {
    const float* mem    = (const float*)d_in[0];
    const float* dim_pe = (const float*)d_in[2];
    const float* vW1    = (const float*)d_in[3];
    const float* vb1    = (const float*)d_in[4];
    const float* vW2    = (const float*)d_in[5];
    const float* vb2    = (const float*)d_in[6];
    const float* hW1    = (const float*)d_in[7];
    const float* hb1    = (const float*)d_in[8];
    const float* hW2    = (const float*)d_in[9];
    const float* hb2    = (const float*)d_in[10];
    const float* projW  = (const float*)d_in[11];
    const float* projb  = (const float*)d_in[12];
    float* out = (float*)d_out;

    _Float16* vbuf = (_Float16*)d_ws;                                   // f16, 16 MB
    float* hbuf = (float*)((char*)d_ws + (size_t)B_ * CL_ * T_ * D_ * sizeof(_Float16));

    k_stage1<<<B_ * CL_ * NTCH_ * 4, 256, 0, stream>>>(mem, dim_pe, vW1, vb1, vW2, vb2, vbuf);
    k_stage2<<<B_ * CL_ * 16 * 4, 256, 0, stream>>>(vbuf, mem, hW1, hb1, hW2, hb2, hbuf);
    k_proj<<<(512 / 32) * (OUT_ / 64), 256, 0, stream>>>(hbuf, projW, projb, out);
}